// Round 10
// baseline (28161.182 us; speedup 1.0000x reference)
//
#include <hip/hip_runtime.h>
#include <hip/hip_fp16.h>

#define TT 512
#define MM 512
#define NWG 512

// ---------------- fast math ----------------
__device__ __forceinline__ float fast_sigmoid(float x) {
  float e = __expf(-x);
  return __builtin_amdgcn_rcpf(1.f + e);
}
__device__ __forceinline__ float fast_tanh(float x) {
  float e = __expf(2.f * x);
  return 1.f - 2.f * __builtin_amdgcn_rcpf(e + 1.f);
}
__device__ __forceinline__ float2 h2f2(unsigned u) {
  __half2 h = *reinterpret_cast<__half2*>(&u);
  return __half22float2(h);
}
__device__ __forceinline__ unsigned pack2(float x, float y) {
  __half2 h = __floats2half2_rn(x, y);
  return *reinterpret_cast<unsigned*>(&h);
}

typedef _Float16 hf2_t __attribute__((ext_vector_type(2)));
__device__ __forceinline__ float fdot2f(unsigned a, unsigned b, float c) {
#if __has_builtin(__builtin_amdgcn_fdot2)
  union U { unsigned u; hf2_t h; };
  U ua, ub; ua.u = a; ub.u = b;
  return __builtin_amdgcn_fdot2(ua.h, ub.h, c, false);
#else
  float2 fa = h2f2(a), fb = h2f2(b);
  return fmaf(fa.x, fb.x, fmaf(fa.y, fb.y, c));
#endif
}

// 24-deep software-pipelined dot: w strided by S (global), x2 in LDS. K%24==0.
template<int K, int S>
__device__ __forceinline__ float dotpipe(const unsigned* __restrict__ w,
                                         const unsigned* __restrict__ x2) {
  unsigned A[12], B[12];
  float acc[4] = {0.f, 0.f, 0.f, 0.f};
  #pragma unroll
  for (int i = 0; i < 12; ++i) A[i] = w[(size_t)i * S];
  #pragma unroll 1
  for (int k = 0; k < K; k += 24) {
    #pragma unroll
    for (int i = 0; i < 12; ++i) B[i] = w[(size_t)(k + 12 + i) * S];
    #pragma unroll
    for (int i = 0; i < 12; ++i) acc[i & 3] = fdot2f(A[i], x2[k + i], acc[i & 3]);
    if (k + 24 < K) {
      #pragma unroll
      for (int i = 0; i < 12; ++i) A[i] = w[(size_t)(k + 24 + i) * S];
    }
    #pragma unroll
    for (int i = 0; i < 12; ++i) acc[i & 3] = fdot2f(B[i], x2[k + 12 + i], acc[i & 3]);
  }
  return (acc[0] + acc[1]) + (acc[2] + acc[3]);
}

// ---------------- agent-scope atomics ----------------
__device__ __forceinline__ void ast(float* p, float v) {
  __hip_atomic_store(p, v, __ATOMIC_RELAXED, __HIP_MEMORY_SCOPE_AGENT);
}
__device__ __forceinline__ float ald(const float* p) {
  return __hip_atomic_load(p, __ATOMIC_RELAXED, __HIP_MEMORY_SCOPE_AGENT);
}
__device__ __forceinline__ void astu(unsigned* p, unsigned v) {
  __hip_atomic_store(p, v, __ATOMIC_RELAXED, __HIP_MEMORY_SCOPE_AGENT);
}
__device__ __forceinline__ unsigned aldu(const unsigned* p) {
  return __hip_atomic_load(p, __ATOMIC_RELAXED, __HIP_MEMORY_SCOPE_AGENT);
}
__device__ __forceinline__ void astull(unsigned long long* p, unsigned long long v) {
  __hip_atomic_store(p, v, __ATOMIC_RELAXED, __HIP_MEMORY_SCOPE_AGENT);
}
__device__ __forceinline__ unsigned long long aldull(const unsigned long long* p) {
  return __hip_atomic_load(p, __ATOMIC_RELAXED, __HIP_MEMORY_SCOPE_AGENT);
}
union F2U { unsigned long long u; float f[2]; };

// ---------------- precompute kernels (verified, unchanged) ----------------
struct ProjParams {
  const float* X[4]; const float* W[4]; __half* C[4]; int rev[4]; int transp[4];
};

__global__ __launch_bounds__(192) void proj_kernel(ProjParams pp) {
  __shared__ float xs[32 * 384];
  const int job = blockIdx.y;
  const float* __restrict__ X = pp.X[job];
  const float* __restrict__ W = pp.W[job];
  __half* __restrict__ C = pp.C[job];
  const int rev = pp.rev[job];
  const int transp = pp.transp[job];
  const int r0 = blockIdx.x * 32;
  const int tid = threadIdx.x;

  for (int idx = tid; idx < 32 * 384; idx += 192) {
    int r = idx / 384, k = idx - r * 384;
    int row = r0 + r;
    int srow = row;
    if (rev) { int t = row >> 6, b2 = row & 63; srow = ((TT - 1 - t) << 6) | b2; }
    xs[idx] = X[(size_t)srow * 384 + k];
  }
  __syncthreads();

  float acc[32];
  #pragma unroll
  for (int r = 0; r < 32; ++r) acc[r] = 0.f;
  for (int k = 0; k < 384; ++k) {
    float w = W[k * 192 + tid];
    #pragma unroll
    for (int r = 0; r < 32; ++r) acc[r] = fmaf(xs[r * 384 + k], w, acc[r]);
  }
  #pragma unroll
  for (int r = 0; r < 32; ++r) {
    int row = r0 + r;
    size_t di = transp ? (((size_t)(row & 63) * MM + (row >> 6)) * 192 + tid)
                       : ((size_t)row * 192 + tid);
    C[di] = __float2half(acc[r]);
  }
}

__global__ __launch_bounds__(384) void memcvt_kernel(const float* __restrict__ src,
                                                     __half* __restrict__ dst) {
  int m = blockIdx.x, b = blockIdx.y, d = threadIdx.x;
  dst[((size_t)b * MM + m) * 384 + d] = __float2half(src[((size_t)m * 64 + b) * 384 + d]);
}

struct WcvtParams { const float* src[8]; unsigned* dst[8]; int tot[8]; int N[8]; };
__global__ __launch_bounds__(256) void wcvt_kernel(WcvtParams wp) {
  int job = blockIdx.y;
  const float* __restrict__ s = wp.src[job];
  unsigned* __restrict__ d = wp.dst[job];
  int n = wp.N[job], tot = wp.tot[job];
  for (int i = blockIdx.x * 256 + threadIdx.x; i < tot; i += gridDim.x * 256) {
    int k2 = i / n, j = i - k2 * n;
    d[i] = pack2(s[(size_t)(2 * k2) * n + j], s[(size_t)(2 * k2 + 1) * n + j]);
  }
}

// ---------------- LDS layout (bytes), quarter variant ----------------
#define L_MP     0         // 128*192 halfs = 49152
#define L_REDP   49152     // 8*384 f = 12288 (B2 partials; later gi partials 576f)
#define L_SH384  61440     // 384 f = 1536
#define L_Q      62976     // 192 f = 768
#define L_XCF    63744     // 768 f = 3072
#define L_XC2    66816     // 384 u = 1536
#define L_G2     68352     // 384 u = 1536
#define L_GHS    69888     // 144 f -> 576 (pad 640)
#define L_HF     70528     // 48 f = 192 (pad 256)
#define L_H2     70784     // 96 u = 384
#define L_VS     71168     // 192 f = 768
#define L_BIH    71936     // 144 f (pad 640)
#define L_BHH    72576     // 144 f (pad 640)
#define L_ZP     73216     // 8 f = 32
#define L_ES     73248     // 128 f = 512
#define SCAN_LDS 73760
static_assert(SCAN_LDS <= 80 * 1024, "need <=80KB for 2 WGs/CU");

struct ScanParams {
  const float* input;        // [512][64][384] f32
  const unsigned* memt;      // [64][512][192] u (384 halfs)
  const unsigned* mpt[2];    // [64][512][96] u ([b][m][a] halfs)
  const __half* xp[2];       // [512][64][192] half
  const unsigned* Wh2[2];    // [96][192] u
  const unsigned* Wg2[2];    // [384][768] u
  const unsigned* Wih2[2];   // [384][576] u
  const unsigned* Whh2[2];   // [96][576] u
  const float* v[2];
  const float* bih[2];
  const float* bhh[2];
  unsigned long long* ectx;  // [dq][2 par][192] f32-pairs
  float* ez;                 // [dq][2 par]
  unsigned* gmail;           // [dq][2 par][96]
  unsigned* hmail;           // [dq][2 par][24]
  unsigned* flags;           // 3 arrays x [dq]  (dq < 512)
  float* out;                // [512][64][384]
};

__global__ __launch_bounds__(512, 4) void scan_kernel(ScanParams p) {
  extern __shared__ char smem[];
  __half*   mp_s   = (__half*)(smem + L_MP);
  float*    redp   = (float*)(smem + L_REDP);
  float*    sh384  = (float*)(smem + L_SH384);
  float*    q_s    = (float*)(smem + L_Q);
  float*    xc_f   = (float*)(smem + L_XCF);
  unsigned* xc2_s  = (unsigned*)(smem + L_XC2);
  unsigned* g2_s   = (unsigned*)(smem + L_G2);
  float*    ghs    = (float*)(smem + L_GHS);
  float*    h_f    = (float*)(smem + L_HF);
  unsigned* h2_s   = (unsigned*)(smem + L_H2);
  float*    v_s    = (float*)(smem + L_VS);
  float*    bih_s  = (float*)(smem + L_BIH);
  float*    bhh_s  = (float*)(smem + L_BHH);
  float*    zp_s   = (float*)(smem + L_ZP);
  float*    e_s    = (float*)(smem + L_ES);

  // mapping: xcd 0-3 -> dir0, 4-7 -> dir1; 4 quarters of a (dir,b) share an XCD
  const int g = blockIdx.x;
  const int xcd = g & 7;
  const int slot = g >> 3;              // 0..63
  const int dir = xcd >> 2;
  const int b = (xcd & 3) * 16 + (slot >> 2);
  const int q = slot & 3;               // m-quarter / col-quarter
  const int tid = threadIdx.x;
  const int lane = tid & 63;
  const int wv = tid >> 6;

  const unsigned* __restrict__ Wh2  = p.Wh2[dir];
  const unsigned* __restrict__ Wg2  = p.Wg2[dir];
  const unsigned* __restrict__ Wih2 = p.Wih2[dir];
  const unsigned* __restrict__ Whh2 = p.Whh2[dir];
  const __half* __restrict__ xp = p.xp[dir];
  const int m0 = 128 * q;

  const int dqb = (dir * 64 + b) * 4;
  const int dq_my = dqb + q;
  const int dq1 = dqb + (q ^ 1), dq2 = dqb + (q ^ 2), dq3 = dqb + (q ^ 3);
  unsigned long long* myctx = p.ectx + (size_t)dq_my * 2 * 192;
  float* myz = p.ez + (size_t)dq_my * 2;
  unsigned* mygm = p.gmail + (size_t)dq_my * 2 * 96;
  unsigned* myhm = p.hmail + (size_t)dq_my * 2 * 24;
  unsigned* fctx = p.flags;            // [512]
  unsigned* fg   = p.flags + 512;
  unsigned* fh   = p.flags + 1024;

  // ---- init ----
  {
    const unsigned* mpu = p.mpt[dir] + ((size_t)b * MM + m0) * 96;
    unsigned* mpd = (unsigned*)mp_s;
    for (int i = tid; i < 128 * 96; i += 512) mpd[i] = mpu[i];
    if (tid < 192) v_s[tid] = p.v[dir][tid];
    if (tid < 96) h2_s[tid] = 0u;
    if (tid < 48) h_f[tid] = 0.f;
    if (tid < 144) {
      int c3 = tid / 48, jj = tid - c3 * 48;
      int col = c3 * 192 + 48 * q + jj;
      bih_s[tid] = p.bih[dir][col];
      bhh_s[tid] = p.bhh[dir][col];
    }
  }
  __syncthreads();
  const float v0 = v_s[lane], v1 = v_s[lane + 64], v2 = v_s[lane + 128];

  #pragma unroll 1
  for (int t = 0; t < TT; ++t) {
    const int par = t & 1;
    const unsigned gen = (unsigned)(t + 1);
    // ---- A: q = xp[t,b,:] + h @ Wh (replicated across quarters) ----
    if (tid < 384) {
      const int kh = (tid >= 192);
      const int a = tid - 192 * kh;
      sh384[tid] = dotpipe<48, 192>(Wh2 + (size_t)kh * 48 * 192 + a, h2_s + kh * 48);
    }
    __syncthreads();
    if (tid < 192)
      q_s[tid] = __half2float(xp[((size_t)t * 64 + b) * 192 + tid]) + sh384[tid] + sh384[192 + tid];
    __syncthreads();

    // ---- B1: scores for my 128 rows (wave-local e_s) ----
    {
      const float q0 = q_s[lane], q1 = q_s[lane + 64], q2 = q_s[lane + 128];
      float zacc = 0.f;
      const __half* mph = mp_s + (wv * 16) * 192;
      #pragma unroll 4
      for (int i = 0; i < 16; ++i) {
        const __half* r = mph + i * 192;
        float s = v0 * fast_tanh(__half2float(r[lane]) + q0)
                + v1 * fast_tanh(__half2float(r[lane + 64]) + q1)
                + v2 * fast_tanh(__half2float(r[lane + 128]) + q2);
        #pragma unroll
        for (int off = 32; off > 0; off >>= 1) s += __shfl_xor(s, off, 64);
        float e = __expf(s);
        zacc += e;
        if (lane == 0) e_s[wv * 16 + i] = e;
      }
      if (lane == 0) zp_s[wv] = zacc;
    }
    // ---- B2: context partial over my 128 rows (wave-local e_s; no barrier) ----
    {
      float ca[8] = {0, 0, 0, 0, 0, 0, 0, 0};
      if (lane < 48) {
        const uint4* mrow4 = (const uint4*)(p.memt + ((size_t)b * MM + m0 + wv * 16) * 192) + lane;
        const float* es = e_s + wv * 16;
        #pragma unroll 8
        for (int i = 0; i < 16; ++i) {
          uint4 mv = mrow4[(size_t)i * 48];
          float e = es[i];
          float2 f0 = h2f2(mv.x), f1 = h2f2(mv.y), f2 = h2f2(mv.z), f3 = h2f2(mv.w);
          ca[0] = fmaf(e, f0.x, ca[0]); ca[1] = fmaf(e, f0.y, ca[1]);
          ca[2] = fmaf(e, f1.x, ca[2]); ca[3] = fmaf(e, f1.y, ca[3]);
          ca[4] = fmaf(e, f2.x, ca[4]); ca[5] = fmaf(e, f2.y, ca[5]);
          ca[6] = fmaf(e, f3.x, ca[6]); ca[7] = fmaf(e, f3.y, ca[7]);
        }
        float2* rp2 = (float2*)(redp + wv * 384 + 8 * lane);
        rp2[0] = make_float2(ca[0], ca[1]);
        rp2[1] = make_float2(ca[2], ca[3]);
        rp2[2] = make_float2(ca[4], ca[5]);
        rp2[3] = make_float2(ca[6], ca[7]);
      }
    }
    __syncthreads();

    // ---- C: combine 8 wave-partials -> mailbox; input row load + pack ----
    const int xt = dir ? (TT - 1 - t) : t;
    const float* xrow = p.input + ((size_t)xt * 64 + b) * 384;
    if (tid < 192) {
      float cm0 = 0.f, cm1 = 0.f;
      const float2* rp2 = (const float2*)redp;
      #pragma unroll
      for (int k = 0; k < 8; ++k) {
        float2 v2r = rp2[k * 192 + tid];
        cm0 += v2r.x; cm1 += v2r.y;
      }
      sh384[2 * tid] = cm0; sh384[2 * tid + 1] = cm1;
      F2U u; u.f[0] = cm0; u.f[1] = cm1;
      astull(myctx + par * 192 + tid, u.u);
      float2 xi = ((const float2*)xrow)[tid];
      xc_f[2 * tid] = xi.x; xc_f[2 * tid + 1] = xi.y;
      xc2_s[tid] = pack2(xi.x, xi.y);
    }
    if (tid == 0) {
      float zs = ((zp_s[0] + zp_s[1]) + (zp_s[2] + zp_s[3]))
               + ((zp_s[4] + zp_s[5]) + (zp_s[6] + zp_s[7]));
      ast(myz + par, zs);
    }
    __syncthreads();   // drains mailbox stores; xc2 input half visible
    if (tid == 0) astu(fctx + dq_my, gen);

    // ---- E1: gate input-half partials (kept in reg); ghs; pollers ----
    float eacc = 0.f;
    if (tid < 384) {
      const int kq = tid / 192, col = tid - kq * 192;
      const int gc = 192 * q + col;
      eacc = dotpipe<96, 768>(Wg2 + (size_t)(kq * 96) * 768 + gc, xc2_s + kq * 96);
    } else if (tid < 504) {
      for (int jj = tid - 384; jj < 144; jj += 120) {
        int c3 = jj / 48;
        int colg = c3 * 192 + 48 * q + (jj - c3 * 48);
        ghs[jj] = dotpipe<96, 576>(Whh2 + colg, h2_s) + bhh_s[jj];
      }
    } else if (tid < 507) {
      const int pdq = dqb + (q ^ (tid - 503));
      while (aldu(fctx + pdq) < gen) __builtin_amdgcn_s_sleep(1);
    }
    __syncthreads();

    // ---- D: assemble ctx (3 partner partials) + build xc ctx half ----
    if (tid < 192) {
      F2U u1, u2, u3;
      u1.u = aldull(p.ectx + ((size_t)dq1 * 2 + par) * 192 + tid);
      u2.u = aldull(p.ectx + ((size_t)dq2 * 2 + par) * 192 + tid);
      u3.u = aldull(p.ectx + ((size_t)dq3 * 2 + par) * 192 + tid);
      float zl = ((zp_s[0] + zp_s[1]) + (zp_s[2] + zp_s[3]))
               + ((zp_s[4] + zp_s[5]) + (zp_s[6] + zp_s[7]));
      float pz = ald(p.ez + (size_t)dq1 * 2 + par) + ald(p.ez + (size_t)dq2 * 2 + par)
               + ald(p.ez + (size_t)dq3 * 2 + par);
      float iz = __builtin_amdgcn_rcpf(zl + pz);
      float x0 = (sh384[2 * tid] + (u1.f[0] + u2.f[0] + u3.f[0])) * iz;
      float x1 = (sh384[2 * tid + 1] + (u1.f[1] + u2.f[1] + u3.f[1])) * iz;
      xc_f[384 + 2 * tid] = x0;
      xc_f[384 + 2 * tid + 1] = x1;
      xc2_s[192 + tid] = pack2(x0, x1);
    }
    __syncthreads();

    // ---- E2: gate ctx-half; publish partials ----
    if (tid < 384) {
      const int kq = tid / 192, col = tid - kq * 192;
      const int gc = 192 * q + col;
      eacc += dotpipe<96, 768>(Wg2 + (size_t)(192 + kq * 96) * 768 + gc, xc2_s + 192 + kq * 96);
      sh384[tid] = eacc;
    }
    __syncthreads();

    // ---- gate combine + g mailbox (own quarter: 96 packed) ----
    if (tid < 96) {
      int c0 = 2 * tid, c1 = 2 * tid + 1;
      float g0 = fast_sigmoid(sh384[c0] + sh384[192 + c0]) * xc_f[192 * q + c0];
      float g1 = fast_sigmoid(sh384[c1] + sh384[192 + c1]) * xc_f[192 * q + c1];
      unsigned pk = pack2(g0, g1);
      g2_s[96 * q + tid] = pk;
      astu(mygm + par * 96 + tid, pk);
    }
    __syncthreads();   // drain
    if (tid == 0) astu(fg + dq_my, gen);

    // ---- gi own-k-quarter partial; pollers ----
    if (tid < 144) {
      int c3 = tid / 48;
      int colg = c3 * 192 + 48 * q + (tid - c3 * 48);
      redp[tid] = dotpipe<96, 576>(Wih2 + (size_t)(96 * q) * 576 + colg, g2_s + 96 * q);
    } else if (tid >= 504 && tid < 507) {
      const int pdq = dqb + (q ^ (tid - 503));
      while (aldu(fg + pdq) < gen) __builtin_amdgcn_s_sleep(1);
    }
    __syncthreads();

    // ---- read partner g quarters ----
    if (tid < 288) {
      int k = tid / 96, j = tid - k * 96;
      int qq = q ^ (k + 1);
      g2_s[96 * qq + j] = aldu(p.gmail + ((size_t)(dqb + qq) * 2 + par) * 96 + j);
    }
    __syncthreads();

    // ---- gi rest: 3 partner k-quarters ----
    if (tid < 432) {
      int j3 = tid / 144, col = tid - j3 * 144;
      int c3 = col / 48;
      int colg = c3 * 192 + 48 * q + (col - c3 * 48);
      int kqq = (q + 1 + j3) & 3;
      redp[144 + tid] = dotpipe<96, 576>(Wih2 + (size_t)(96 * kqq) * 576 + colg, g2_s + 96 * kqq);
    }
    __syncthreads();

    // ---- H: GRU update (my 48 cols, 2/thread) + out + h mailbox ----
    if (tid < 24) {
      int trow = dir ? (TT - 1 - t) : t;
      float2* orow = (float2*)(p.out + ((size_t)trow * 64 + b) * 384 + dir * 192 + 48 * q);
      float hn[2];
      #pragma unroll
      for (int s2 = 0; s2 < 2; ++s2) {
        int jj = 2 * tid + s2;
        float gi_r = redp[jj]       + redp[144 + 0 * 144 + jj] + redp[144 + 1 * 144 + jj] + redp[144 + 2 * 144 + jj] + bih_s[jj];
        float gi_z = redp[48 + jj]  + redp[144 + 0 * 144 + 48 + jj] + redp[144 + 1 * 144 + 48 + jj] + redp[144 + 2 * 144 + 48 + jj] + bih_s[48 + jj];
        float gi_n = redp[96 + jj]  + redp[144 + 0 * 144 + 96 + jj] + redp[144 + 1 * 144 + 96 + jj] + redp[144 + 2 * 144 + 96 + jj] + bih_s[96 + jj];
        float r = fast_sigmoid(gi_r + ghs[jj]);
        float z = fast_sigmoid(gi_z + ghs[48 + jj]);
        float n = fast_tanh(gi_n + r * ghs[96 + jj]);
        hn[s2] = (1.f - z) * n + z * h_f[jj];
        h_f[jj] = hn[s2];
      }
      orow[tid] = make_float2(hn[0], hn[1]);
      unsigned pk = pack2(hn[0], hn[1]);
      h2_s[24 * q + tid] = pk;
      astu(myhm + par * 24 + tid, pk);
    }
    __syncthreads();   // drain
    if (tid == 0) astu(fh + dq_my, gen);
    if (tid >= 504 && tid < 507) {
      const int pdq = dqb + (q ^ (tid - 503));
      while (aldu(fh + pdq) < gen) __builtin_amdgcn_s_sleep(1);
    }
    __syncthreads();
    if (tid < 72) {
      int k = tid / 24, j = tid - k * 24;
      int qq = q ^ (k + 1);
      h2_s[24 * qq + j] = aldu(p.hmail + ((size_t)(dqb + qq) * 2 + par) * 24 + j);
    }
    __syncthreads();
  }
}

// ---------------- launcher ----------------
extern "C" void kernel_launch(void* const* d_in, const int* in_sizes, int n_in,
                              void* d_out, int out_size, void* d_ws, size_t ws_size,
                              hipStream_t stream) {
  (void)in_sizes; (void)n_in; (void)out_size;
  const float* memory = (const float*)d_in[0];
  const float* input  = (const float*)d_in[2];
  const float* Wm[2]  = {(const float*)d_in[3],  (const float*)d_in[12]};
  const float* Wx[2]  = {(const float*)d_in[4],  (const float*)d_in[13]};
  const float* Wh[2]  = {(const float*)d_in[5],  (const float*)d_in[14]};
  const float* v[2]   = {(const float*)d_in[6],  (const float*)d_in[15]};
  const float* Wg[2]  = {(const float*)d_in[7],  (const float*)d_in[16]};
  const float* Wih[2] = {(const float*)d_in[8],  (const float*)d_in[17]};
  const float* Whh[2] = {(const float*)d_in[9],  (const float*)d_in[18]};
  const float* bih[2] = {(const float*)d_in[10], (const float*)d_in[19]};
  const float* bhh[2] = {(const float*)d_in[11], (const float*)d_in[20]};

  char* ws = (char*)d_ws;
  const size_t OFF_FLAGS = 0;          // 3*512*4 = 6144 -> pad 8192
  const size_t OFF_EZ    = 8192;       // 512*2*4 = 4096
  const size_t OFF_GMAIL = 12288;      // 512*2*96*4 = 393216
  const size_t OFF_HMAIL = 405504;     // 512*2*24*4 = 98304
  const size_t OFF_ECTX  = 503808;     // 512*2*192*8 = 1572864
  const size_t OFF_MPT0  = 2076672;
  const size_t OFF_MPT1  = OFF_MPT0 + 12582912;
  const size_t OFF_XP0   = OFF_MPT1 + 12582912;
  const size_t OFF_XP1   = OFF_XP0 + 12582912;
  const size_t OFF_MT    = OFF_XP1 + 12582912;
  const size_t OFF_WG0   = OFF_MT + 25165824;
  const size_t OFF_WG1   = OFF_WG0 + 1179648;
  const size_t OFF_WIH0  = OFF_WG1 + 1179648;
  const size_t OFF_WIH1  = OFF_WIH0 + 884736;
  const size_t OFF_WHH0  = OFF_WIH1 + 884736;
  const size_t OFF_WHH1  = OFF_WHH0 + 221184;
  const size_t OFF_WH0   = OFF_WHH1 + 221184;
  const size_t OFF_WH1   = OFF_WH0 + 73728;
  const size_t NEEDED    = OFF_WH1 + 73728;   // ~82.4 MB
  if (ws_size < NEEDED) return;

  unsigned* flags = (unsigned*)(ws + OFF_FLAGS);
  float* ez    = (float*)(ws + OFF_EZ);
  unsigned* gmail = (unsigned*)(ws + OFF_GMAIL);
  unsigned* hmail = (unsigned*)(ws + OFF_HMAIL);
  unsigned long long* ectx = (unsigned long long*)(ws + OFF_ECTX);
  __half* mpt0 = (__half*)(ws + OFF_MPT0);
  __half* mpt1 = (__half*)(ws + OFF_MPT1);
  __half* xp0  = (__half*)(ws + OFF_XP0);
  __half* xp1  = (__half*)(ws + OFF_XP1);
  __half* memt = (__half*)(ws + OFF_MT);
  unsigned* wg2[2]  = {(unsigned*)(ws + OFF_WG0),  (unsigned*)(ws + OFF_WG1)};
  unsigned* wih2[2] = {(unsigned*)(ws + OFF_WIH0), (unsigned*)(ws + OFF_WIH1)};
  unsigned* whh2[2] = {(unsigned*)(ws + OFF_WHH0), (unsigned*)(ws + OFF_WHH1)};
  unsigned* wh2[2]  = {(unsigned*)(ws + OFF_WH0),  (unsigned*)(ws + OFF_WH1)};

  hipFuncSetAttribute(reinterpret_cast<const void*>(scan_kernel),
                      hipFuncAttributeMaxDynamicSharedMemorySize, SCAN_LDS);

  hipMemsetAsync(ws + OFF_FLAGS, 0, 8192, stream);   // flags only

  ProjParams pp;
  pp.X[0] = memory; pp.W[0] = Wm[0]; pp.C[0] = mpt0; pp.rev[0] = 0; pp.transp[0] = 1;
  pp.X[1] = memory; pp.W[1] = Wm[1]; pp.C[1] = mpt1; pp.rev[1] = 0; pp.transp[1] = 1;
  pp.X[2] = input;  pp.W[2] = Wx[0]; pp.C[2] = xp0;  pp.rev[2] = 0; pp.transp[2] = 0;
  pp.X[3] = input;  pp.W[3] = Wx[1]; pp.C[3] = xp1;  pp.rev[3] = 1; pp.transp[3] = 0;
  proj_kernel<<<dim3(1024, 4), dim3(192), 0, stream>>>(pp);
  memcvt_kernel<<<dim3(MM, 64), dim3(384), 0, stream>>>(memory, memt);

  WcvtParams wp;
  for (int d = 0; d < 2; ++d) {
    wp.src[d]     = Wg[d];  wp.dst[d]     = wg2[d];  wp.tot[d]     = 384 * 768; wp.N[d]     = 768;
    wp.src[2 + d] = Wih[d]; wp.dst[2 + d] = wih2[d]; wp.tot[2 + d] = 384 * 576; wp.N[2 + d] = 576;
    wp.src[4 + d] = Whh[d]; wp.dst[4 + d] = whh2[d]; wp.tot[4 + d] = 96 * 576;  wp.N[4 + d] = 576;
    wp.src[6 + d] = Wh[d];  wp.dst[6 + d] = wh2[d];  wp.tot[6 + d] = 96 * 192;  wp.N[6 + d] = 192;
  }
  wcvt_kernel<<<dim3(288, 8), dim3(256), 0, stream>>>(wp);

  ScanParams sp;
  sp.input = input;
  sp.memt = (const unsigned*)memt;
  sp.mpt[0] = (const unsigned*)mpt0; sp.mpt[1] = (const unsigned*)mpt1;
  sp.xp[0] = xp0; sp.xp[1] = xp1;
  for (int d = 0; d < 2; ++d) {
    sp.Wh2[d] = wh2[d]; sp.Wg2[d] = wg2[d]; sp.Wih2[d] = wih2[d]; sp.Whh2[d] = whh2[d];
    sp.v[d] = v[d]; sp.bih[d] = bih[d]; sp.bhh[d] = bhh[d];
  }
  sp.ectx = ectx; sp.ez = ez; sp.gmail = gmail; sp.hmail = hmail; sp.flags = flags;
  sp.out = (float*)d_out;
  scan_kernel<<<dim3(NWG), dim3(512), SCAN_LDS, stream>>>(sp);
}